// Round 10
// baseline (95.808 us; speedup 1.0000x reference)
//
#include <hip/hip_runtime.h>
#include <stdint.h>

#define NN 2048
#define LL 21
#define CAP 200
#define TOT (LL * CAP)
#define TMAX 320                 // matrix-resolve candidate window (5 chunks of 64)
#define NCH (TMAX / 64)
#define NBK 1024                 // score buckets
#define ARRCAP 1200

typedef unsigned long long u64;
typedef unsigned int u32;

__device__ __forceinline__ u64 shfl_u64(u64 v, int lane) {
    int lo = (int)(u32)(v & 0xFFFFFFFFull);
    int hi = (int)(u32)(v >> 32);
    lo = __shfl(lo, lane);
    hi = __shfl(hi, lane);
    return ((u64)(u32)hi << 32) | (u32)lo;
}

__device__ __forceinline__ u64 shfl_xor_u64(u64 v, int mask) {
    int lo = (int)(u32)(v & 0xFFFFFFFFull);
    int hi = (int)(u32)(v >> 32);
    lo = __shfl_xor(lo, mask);
    hi = __shfl_xor(hi, mask);
    return ((u64)(u32)hi << 32) | (u32)lo;
}

__device__ __forceinline__ float4 clip01(float4 b) {
    b.x = fminf(fmaxf(b.x, 0.0f), 1.0f);
    b.y = fminf(fmaxf(b.y, 0.0f), 1.0f);
    b.z = fminf(fmaxf(b.z, 0.0f), 1.0f);
    b.w = fminf(fmaxf(b.w, 0.0f), 1.0f);
    return b;
}

// decode, exact np op order (absmax 0.0 in R1-R9)
__device__ __forceinline__ float4 decode_box(const float4 roi, const float4 dd) {
#pragma clang fp contract(off)
    float h  = roi.z - roi.x;
    float w  = roi.w - roi.y;
    float cy = roi.x + 0.5f * h;
    float cx = roi.y + 0.5f * w;
    float d0 = dd.x * 0.1f;
    float d1 = dd.y * 0.1f;
    float d2 = dd.z * 0.2f;
    float d3 = dd.w * 0.2f;
    float nh = (float)exp((double)d2) * h;
    float nw = (float)exp((double)d3) * w;
    float ncy = d0 * h + cy;
    float ncx = d1 * w + cx;
    return make_float4(ncy - 0.5f * nh, ncx - 0.5f * nw, ncy + 0.5f * nh, ncx + 0.5f * nw);
}

__device__ __forceinline__ float area_of(const float4 b) {
#pragma clang fp contract(off)
    return (b.z - b.x) * (b.w - b.y);   // same expr/order as reference
}

__device__ __forceinline__ bool iou_gt(const float4 a, const float4 b) {
#pragma clang fp contract(off)
    float areaA = (a.z - a.x) * (a.w - a.y);
    float areaB = (b.z - b.x) * (b.w - b.y);
    float ih = fminf(a.z, b.z) - fmaxf(a.x, b.x);
    ih = fmaxf(ih, 0.0f);
    float iw = fminf(a.w, b.w) - fmaxf(a.y, b.y);
    iw = fmaxf(iw, 0.0f);
    float inter = ih * iw;
    float denom = ((areaA + areaB) - inter) + 1e-9f;
    return (inter / denom) > 0.5f;
}

// same decision with precomputed areas (identical FP expressions/order)
__device__ __forceinline__ bool iou_gt_pre(const float4 a, const float4 b,
                                           float areaA, float areaB) {
#pragma clang fp contract(off)
    float ih = fminf(a.z, b.z) - fmaxf(a.x, b.x);
    ih = fmaxf(ih, 0.0f);
    float iw = fminf(a.w, b.w) - fmaxf(a.y, b.y);
    iw = fmaxf(iw, 0.0f);
    float inter = ih * iw;
    float denom = ((areaA + areaB) - inter) + 1e-9f;
    return (inter / denom) > 0.5f;
}

// reverse-bucket: rb=0 is the HIGHEST score bucket (descending order)
__device__ __forceinline__ int rb_of(u64 key) {
    u32 sb = (u32)(key >> 32);                 // score bits in (0x3F000000, 0x3F800000)
    int rb = 1023 - (int)((sb - 0x3F000000u) >> 13);
    return min(max(rb, 0), 1023);
}

__device__ __forceinline__ u64 lowmask(int n) {
    return (n >= 64) ? ~0ull : ((1ull << n) - 1ull);
}

// descending exclusive scan of histR[1024] -> dstart & cursor
template <int NTHR>
__device__ __forceinline__ void desc_scan(int* histR, int* dstart, int* cursor,
                                          int* wtot, int t) {
    const int PB = NBK / NTHR;
    const int NW = NTHR / 64;
    const int lane = t & 63, w = t >> 6;
    int c[PB], local = 0;
    for (int k = 0; k < PB; ++k) { c[k] = histR[PB * t + k]; local += c[k]; }
    int incl = local;
    for (int d = 1; d < 64; d <<= 1) {
        int v = __shfl_up(incl, d);
        if (lane >= d) incl += v;
    }
    if (lane == 63) wtot[w] = incl;
    __syncthreads();
    int woff = 0;
    for (int i = 0; i < w && i < NW; ++i) woff += wtot[i];
    int run = woff + incl - local;
    for (int k = 0; k < PB; ++k) {
        dstart[PB * t + k] = run;
        cursor[PB * t + k] = run;
        run += c[k];
    }
    __syncthreads();
}

// ------ Kernel B: coalesced score phase + grid barrier + sort + matrix NMS ---
// Arena: A0=[0,17408) phase0 tile (10.5KB) / skey / skey3 ;
//        A1=[17408,34816) skey2 (P7 reuse: sup|extq) ;
//        A2=[34816,47104) histR|cursor|dstart ;
//        A3=[47104,63104) cbox(5120)|R(2560)|Tm(5120)|kept(3200) ;
//        A4=[63104,64384) area[320]
#define SMEM_B 64384
#define A1OFF 17408
#define A2OFF 34816
#define A3OFF 47104
#define A4OFF 63104

__global__ __launch_bounds__(1024, 1) void per_class_kernel(
    const float* __restrict__ probs,    // (N, L)
    const float* __restrict__ roi,      // (N,4)
    const float* __restrict__ deltas,   // (N, L*4)
    u32* __restrict__ scoreT,           // (L, N) score bits staging
    u64* __restrict__ cand_key,         // (L*CAP)
    float4* __restrict__ cand_box,      // (L*CAP)
    u64* __restrict__ fb_key,           // (L)
    float4* __restrict__ fb_box,        // (L)
    u32* __restrict__ ctr,              // [1] arrival counter (memset 0)
    u32* __restrict__ ghist)            // [NBK] global hist (memset 0)
{
    const int cls = blockIdx.x;
    const int t = threadIdx.x;
    const int lane = t & 63;

    __shared__ char sm[SMEM_B];
    __shared__ int sCnt, sK;
    __shared__ u64 sGmax;
    __shared__ u64 keepm[NCH];
    __shared__ int wtot[16];

    u64* skey  = (u64*)sm;
    u64* skey3 = (u64*)sm;                  // overwrites skey after it's consumed
    u64* skey2 = (u64*)(sm + A1OFF);
    int* histR  = (int*)(sm + A2OFF);
    int* cursor = (int*)(sm + A2OFF + 4096);
    int* dstart = (int*)(sm + A2OFF + 8192);
    float4* cbox = (float4*)(sm + A3OFF);            // [TMAX]
    u64* R  = (u64*)(sm + A3OFF + 5120);             // [NCH*64]
    u64* Tm = (u64*)(sm + A3OFF + 7680);             // [10*64]
    float4* kept = (float4*)(sm + A3OFF + 12800);    // [CAP]
    float* area = (float*)(sm + A4OFF);              // [TMAX]

    if (t == 0) { sCnt = 0; sK = 0; sGmax = 0ull; }
    if (t < CAP) cand_key[cls * CAP + t] = 0ull;
    histR[t] = 0;

    // P0: blocks 0..15 compute scoreT for anchors [b*128, b*128+128), COALESCED
    // (score_kernel's exact pattern). Blocks 16..20 go straight to the barrier.
    if (cls < 16) {
        float* tile = (float*)sm;                  // 128*21 floats = 10.5 KB (in A0)
        const int a0 = cls * 128;
        const float4* src = (const float4*)(probs + a0 * LL);   // 10752 B, 16-aligned
        float4* dst = (float4*)tile;
        if (t < 672) dst[t] = src[t];
        __syncthreads();
        if (t < 128) {
            const float* row = tile + t * LL;      // stride 21 (odd): conflict-light
            float best = row[0];
            int bi = 0;
            for (int j = 1; j < LL; ++j) {
                float v = row[j];
                if (v > best) { best = v; bi = j; }
            }
            for (int c = 0; c < LL; ++c)           // per-c: 128 consecutive u32 stores
                scoreT[c * NN + a0 + t] = (bi != 0) ? __float_as_uint(row[c]) : 0u;
        }
        __syncthreads();                           // tile dead; A0 reusable
    }

    // Grid barrier (R8-validated): release scoreT, spin until all 21 arrived.
    __threadfence();
    if (t == 0) {
        __hip_atomic_fetch_add(&ctr[0], 1u, __ATOMIC_ACQ_REL, __HIP_MEMORY_SCOPE_AGENT);
        while (__hip_atomic_load(&ctr[0], __ATOMIC_ACQUIRE, __HIP_MEMORY_SCOPE_AGENT)
               < (u32)LL) {}
    }
    __syncthreads();

    // P1: own-class scores via agent-scope loads, compact > 0.5, hist + block max
    u32 sv[2];
    sv[0] = __hip_atomic_load(scoreT + cls * NN + 2 * t,     __ATOMIC_RELAXED,
                              __HIP_MEMORY_SCOPE_AGENT);
    sv[1] = __hip_atomic_load(scoreT + cls * NN + 2 * t + 1, __ATOMIC_RELAXED,
                              __HIP_MEMORY_SCOPE_AGENT);
    u64 lq[2];
    int ln = 0;
    u64 lmax = 0ull;
    for (int k = 0; k < 2; ++k) {
        u32 a = 2 * t + k;
        u64 key = ((u64)sv[k] << 32) | (u32)(~a);
        if (key > lmax) lmax = key;
        if (sv[k] > 0x3F000000u) lq[ln++] = key;   // strict score > 0.5
    }
    for (int d = 1; d < 64; d <<= 1) {
        u64 o = shfl_xor_u64(lmax, d);
        if (o > lmax) lmax = o;
    }
    if (lane == 0) atomicMax(&sGmax, lmax);
    int incl = ln;
    for (int d = 1; d < 64; d <<= 1) {
        int v = __shfl_up(incl, d);
        if (lane >= d) incl += v;
    }
    int wsum = __shfl(incl, 63);
    int wbase = 0;
    if (lane == 63) wbase = atomicAdd(&sCnt, wsum);
    wbase = __shfl(wbase, 63);
    int off = wbase + incl - ln;
    for (int j = 0; j < ln; ++j) {
        skey[off + j] = lq[j];
        atomicAdd(&histR[rb_of(lq[j])], 1);
    }
    __syncthreads();
    const int M = sCnt;
    const int TT = min(M, TMAX);

    // per-class fallback: rank-0 box (always kept); max over ALL scores
    if (t == 0) {
        u64 g = sGmax;
        u32 a0 = ~(u32)(g & 0xFFFFFFFFull);
        float4 rb = *(const float4*)(roi + a0 * 4);
        float4 dd = *(const float4*)(deltas + a0 * (LL * 4) + cls * 4);
        fb_box[cls] = decode_box(rb, dd);
        fb_key[cls] = (g & 0xFFFFFFFF00000000ull) | (u32)(~(u32)(cls * NN));
    }

    // P2: scan
    desc_scan<1024>(histR, dstart, cursor, wtot, t);

    // P3: scatter to bucket-grouped order (1 element/thread typical)
    for (int i = t; i < M; i += 1024) {
        u64 k = skey[i];
        int pos = atomicAdd(&cursor[rb_of(k)], 1);
        skey2[pos] = k;
    }
    __syncthreads();   // skey consumed -> region becomes skey3

    // P4: rank-by-count -> sorted skey3 ; fused decode+area for rnk < TT
    for (int p = t; p < M; p += 1024) {
        u64 k = skey2[p];
        int rb = rb_of(k);
        int s = dstart[rb], e = s + histR[rb];
        int rnk = s;
        for (int q = s; q < e; ++q) rnk += (skey2[q] > k) ? 1 : 0;  // independent reads
        skey3[rnk] = k;
        if (rnk < TT) {
            u32 a = ~(u32)(k & 0xFFFFFFFFull);
            float4 rbx = *(const float4*)(roi + a * 4);
            float4 dd = *(const float4*)(deltas + a * (LL * 4) + cls * 4);
            float4 bx = decode_box(rbx, dd);
            cbox[rnk] = bx;
            area[rnk] = area_of(bx);
        }
    }
    __syncthreads();   // skey2 dead

    const int NCHe = (TT + 63) / 64;
    const int NJ = NCHe * (NCHe + 1) / 2;            // jobs (cj,ci) ci<=cj

    // P5: pair-bit matrix with precomputed areas (<=1 task/thread at 1024)
    for (int task = t; task < NJ * 64; task += 1024) {
        const int jobid = task >> 6, j = task & 63;
        int cj = 0, acc = 0;
        while (acc + cj + 1 <= jobid) { acc += cj + 1; ++cj; }
        const int ci = jobid - acc;
        const int gj = cj * 64 + j;
        const int nbj = min(64, TT - cj * 64);
        if (ci == cj) {
            u64 row = 0ull;
            if (j < nbj) {
                float4 bj = cbox[gj];
                float aj = area[gj];
                for (int r2 = j + 1; r2 < nbj; ++r2)
                    if (iou_gt_pre(bj, cbox[cj * 64 + r2], aj, area[cj * 64 + r2]))
                        row |= (1ull << r2);
            }
            R[cj * 64 + j] = row;
        } else {
            u64 wd = 0ull;
            if (j < nbj) {
                float4 bj = cbox[gj];
                float aj = area[gj];
                const float4* cb = cbox + ci * 64;   // broadcast reads
                const float* ca = area + ci * 64;
                for (int i = 0; i < 64; ++i)
                    if (iou_gt_pre(cb[i], bj, ca[i], aj)) wd |= (1ull << i);
            }
            Tm[(cj * (cj - 1) / 2 + ci) * 64 + j] = wd;
        }
    }
    __syncthreads();

    // P6: wave0 barrier-free resolve with sparse skip (overlaps rare)
    if (t < 64) {
        int K = 0;
        for (int cj = 0; cj < NCHe; ++cj) {
            if (K >= CAP) break;
            const int nb = min(64, TT - cj * 64);
            u64 row = R[cj * 64 + t];
            bool ext = (t >= nb);
            for (int ci = 0; ci < cj; ++ci)
                if (Tm[(cj * (cj - 1) / 2 + ci) * 64 + t] & keepm[ci]) ext = true;
            u64 rem = __ballot(ext);
            const u64 nz = __ballot(row != 0ull) & ~rem;
            u64 m = nz;
            while (m) {
                int i = __ffsll(m) - 1;
                u64 ri = shfl_u64(row, i);
                rem |= ri;
                u64 gt = (i == 63) ? 0ull : ~lowmask(i + 1);
                m = nz & ~rem & gt;
            }
            u64 keep = ~rem & lowmask(nb);
            if (t == 0) keepm[cj] = keep;
            if (t < nb && ((keep >> t) & 1ull)) {
                int krank = K + __popcll(keep & lowmask(t));
                if (krank < CAP) {
                    kept[krank] = cbox[cj * 64 + t];
                    int slot = cls * CAP + krank;
                    u64 key = (skey3[cj * 64 + t] & 0xFFFFFFFF00000000ull) |
                              (u32)(~(u32)slot);
                    // ~slot low bits: slot order isomorphic to flat-index order ->
                    // reproduces lax.top_k stable tie-break
                    cand_key[slot] = key;
                    cand_box[slot] = cbox[cj * 64 + t];
                    atomicAdd(&ghist[rb_of(key)], 1u);   // device-scope global hist
                }
            }
            K += __popcll(keep);
        }
        if (t == 0) sK = K;
    }
    __syncthreads();

    // P7: rare exact continuation past TMAX (16 groups of 64; scratch in dead skey2)
    int K = sK;
    if (K < CAP && M > TT) {
        u64* sup = (u64*)(sm + A1OFF);                       // [16][64] = 8 KB
        unsigned char* extq = (unsigned char*)(sm + A1OFF + 8192);  // [16][64]
        const int g = t >> 6, r = t & 63;
        for (int base = TT; base < M; base += 64) {
            K = sK;
            if (K >= CAP) break;
            const int nb = min(64, M - base);
            if (t < nb) {
                u32 a = ~(u32)(skey3[base + t] & 0xFFFFFFFFull);
                float4 rbx = *(const float4*)(roi + a * 4);
                float4 dd = *(const float4*)(deltas + a * (LL * 4) + cls * 4);
                cbox[t] = decode_box(rbx, dd);
            }
            __syncthreads();
            u64 bits = 0ull;
            if (r < nb) {
                float4 br = cbox[r];
                int lo = max(r + 1, g * 4), hi = min(nb, (g + 1) * 4);
                for (int r2 = lo; r2 < hi; ++r2)
                    if (iou_gt(br, cbox[r2])) bits |= (1ull << r2);
            }
            sup[g * 64 + r] = bits;
            bool f = false;
            if (r < nb) {
                float4 bm = cbox[r];
                int per = (K + 15) >> 4;
                int e0 = g * per, e1 = min(K, e0 + per);
                for (int e = e0; e < e1; ++e)
                    if (iou_gt(kept[e], bm)) { f = true; break; }
            }
            extq[g * 64 + r] = f ? 1 : 0;
            __syncthreads();
            if (t < 64) {
                u64 row = 0ull;
                int extv = 0;
                for (int j = 0; j < 16; ++j) { row |= sup[j * 64 + t]; extv |= extq[j * 64 + t]; }
                bool ext = (t < nb) ? (extv != 0) : true;
                u64 rem = __ballot(ext);
                const u64 nz = __ballot(row != 0ull) & ~rem;
                u64 m = nz;
                while (m) {
                    int i = __ffsll(m) - 1;
                    u64 ri = shfl_u64(row, i);
                    rem |= ri;
                    u64 gt = (i == 63) ? 0ull : ~lowmask(i + 1);
                    m = nz & ~rem & gt;
                }
                u64 keep = ~rem & lowmask(nb);
                if (t < nb && ((keep >> t) & 1ull)) {
                    int krank = K + __popcll(keep & lowmask(t));
                    if (krank < CAP) {
                        kept[krank] = cbox[t];
                        int slot = cls * CAP + krank;
                        u64 key = (skey3[base + t] & 0xFFFFFFFF00000000ull) |
                                  (u32)(~(u32)slot);
                        cand_key[slot] = key;
                        cand_box[slot] = cbox[t];
                        atomicAdd(&ghist[rb_of(key)], 1u);
                    }
                }
                if (t == 0) sK = K + __popcll(keep);
            }
            __syncthreads();
        }
    }
}

// -------- Kernel C: global top-200 using precomputed ghist (512 threads) -----
__global__ __launch_bounds__(512) void topk_kernel(
    const u64* __restrict__ cand_key,
    const float4* __restrict__ cand_box,
    const u64* __restrict__ fb_key,
    const float4* __restrict__ fb_box,
    const u32* __restrict__ ghist,
    float* __restrict__ out)   // [800 boxes][200 labels][200 scores]
{
    const int t = threadIdx.x;
    __shared__ int histR[NBK], cursor[NBK], dstart[NBK];
    __shared__ u64 arr[ARRCAP];
    __shared__ u64 outk[CAP];
    __shared__ int wtot[8];
    __shared__ int sRbstar;

    histR[2 * t]     = (int)ghist[2 * t];       // coalesced global hist load
    histR[2 * t + 1] = (int)ghist[2 * t + 1];
    if (t < CAP) outk[t] = 0ull;
    if (t == 0) sRbstar = NBK - 1;
    __syncthreads();

    desc_scan<512>(histR, dstart, cursor, wtot, t);
    // unique crossing bucket: dstart < CAP <= dstart+len (single writer, no storm)
    for (int k = 0; k < 2; ++k) {
        int rb = 2 * t + k;
        if (dstart[rb] < CAP && dstart[rb] + histR[rb] >= CAP) sRbstar = rb;
    }
    __syncthreads();
    const int rbstar = sRbstar;

    // single pass over cand_key: scatter survivors (rb <= rbstar) to arr
    const ulong2* ck2 = (const ulong2*)cand_key;
    for (int i = t; i < TOT / 2; i += 512) {
        ulong2 k2 = ck2[i];
        if (k2.x != 0ull) {
            int rb = rb_of(k2.x);
            if (rb <= rbstar) {
                int pos = atomicAdd(&cursor[rb], 1);
                if (pos < ARRCAP) arr[pos] = k2.x;
            }
        }
        if (k2.y != 0ull) {
            int rb = rb_of(k2.y);
            if (rb <= rbstar) {
                int pos = atomicAdd(&cursor[rb], 1);
                if (pos < ARRCAP) arr[pos] = k2.y;
            }
        }
    }
    __syncthreads();

    // rank-by-count within buckets: exact global rank, direct scatter to outk
    const int E = min(dstart[rbstar] + histR[rbstar], ARRCAP);
    for (int p = t; p < E; p += 512) {
        u64 k = arr[p];
        int rb = rb_of(k);
        int s = dstart[rb], e = min(s + histR[rb], ARRCAP);
        int rnk = s;
        for (int q = s; q < e; ++q) rnk += (arr[q] > k) ? 1 : 0;  // independent reads
        if (rnk < CAP) outk[rnk] = k;
    }
    __syncthreads();

    for (int o = t; o < CAP; o += 512) {
        u64 key = outk[o];
        float4 b = make_float4(0.0f, 0.0f, 0.0f, 0.0f);
        float lab = 0.0f, sc = 0.0f;
        if (key != 0ull) {   // all candidates have score > 0.5 -> valid
            u32 slot = ~(u32)(key & 0xFFFFFFFFull);
            sc = __uint_as_float((u32)(key >> 32));
            lab = (float)(slot / CAP);
            b = clip01(cand_box[slot]);
        }
        out[o * 4 + 0] = b.x;
        out[o * 4 + 1] = b.y;
        out[o * 4 + 2] = b.z;
        out[o * 4 + 3] = b.w;
        out[4 * CAP + o] = lab;
        out[5 * CAP + o] = sc;
    }
    __syncthreads();

    // fallback: no candidate anywhere -> global best kept box at slot 0
    if (t == 0 && outk[0] == 0ull) {
        u64 best = 0ull;
        int bc = 0;
        for (int c = 0; c < LL; ++c) {
            u64 k = fb_key[c];
            if (k > best) { best = k; bc = c; }
        }
        float bs = __uint_as_float((u32)(best >> 32));
        if (bs >= 0.001f) {
            float4 bb = clip01(fb_box[bc]);
            out[0] = bb.x; out[1] = bb.y; out[2] = bb.z; out[3] = bb.w;
            out[4 * CAP] = (float)bc;
            out[5 * CAP] = bs;
        }
    }
}

extern "C" void kernel_launch(void* const* d_in, const int* in_sizes, int n_in,
                              void* d_out, int out_size, void* d_ws, size_t ws_size,
                              hipStream_t stream) {
    const float* roi    = (const float*)d_in[0];   // (1,2048,4)
    const float* deltas = (const float*)d_in[1];   // (1,2048,84)
    const float* probs  = (const float*)d_in[2];   // (1,2048,21)
    float* out = (float*)d_out;

    char* ws = (char*)d_ws;
    u32*    scoreT   = (u32*)ws;                   // 21*2048*4 = 172032
    u64*    cand_key = (u64*)(ws + 172032);        // 4200*8   = 33600 -> 205632
    float4* cand_box = (float4*)(ws + 205632);     // 4200*16  = 67200 -> 272832
    u64*    fb_key   = (u64*)(ws + 272832);        // 168 -> 273000
    float4* fb_box   = (float4*)(ws + 273008);     // 336 -> 273344
    u32*    ctr      = (u32*)(ws + 273344);        // 8 B
    u32*    ghist    = (u32*)(ws + 273352);        // 4096 B

    (void)hipMemsetAsync(ctr, 0, 8 + NBK * 4, stream);   // ctr + ghist in one node
    per_class_kernel<<<LL, 1024, 0, stream>>>(probs, roi, deltas, scoreT,
                                              cand_key, cand_box, fb_key, fb_box,
                                              ctr, ghist);
    topk_kernel<<<1, 512, 0, stream>>>(cand_key, cand_box, fb_key, fb_box, ghist, out);
}

// Round 11
// 87.562 us; speedup vs baseline: 1.0942x; 1.0942x over previous
//
#include <hip/hip_runtime.h>
#include <stdint.h>

#define NN 2048
#define LL 21
#define CAP 200
#define TOT (LL * CAP)
#define TMAX 320                 // matrix-resolve candidate window (5 chunks of 64)
#define NCH (TMAX / 64)
#define NBK 1024                 // score buckets
#define ARRCAP 1200

typedef unsigned long long u64;
typedef unsigned int u32;

__device__ __forceinline__ u64 shfl_u64(u64 v, int lane) {
    int lo = (int)(u32)(v & 0xFFFFFFFFull);
    int hi = (int)(u32)(v >> 32);
    lo = __shfl(lo, lane);
    hi = __shfl(hi, lane);
    return ((u64)(u32)hi << 32) | (u32)lo;
}

__device__ __forceinline__ u64 shfl_xor_u64(u64 v, int mask) {
    int lo = (int)(u32)(v & 0xFFFFFFFFull);
    int hi = (int)(u32)(v >> 32);
    lo = __shfl_xor(lo, mask);
    hi = __shfl_xor(hi, mask);
    return ((u64)(u32)hi << 32) | (u32)lo;
}

__device__ __forceinline__ float4 clip01(float4 b) {
    b.x = fminf(fmaxf(b.x, 0.0f), 1.0f);
    b.y = fminf(fmaxf(b.y, 0.0f), 1.0f);
    b.z = fminf(fmaxf(b.z, 0.0f), 1.0f);
    b.w = fminf(fmaxf(b.w, 0.0f), 1.0f);
    return b;
}

// decode, exact np op order (absmax 0.0 in R1-R10)
__device__ __forceinline__ float4 decode_box(const float4 roi, const float4 dd) {
#pragma clang fp contract(off)
    float h  = roi.z - roi.x;
    float w  = roi.w - roi.y;
    float cy = roi.x + 0.5f * h;
    float cx = roi.y + 0.5f * w;
    float d0 = dd.x * 0.1f;
    float d1 = dd.y * 0.1f;
    float d2 = dd.z * 0.2f;
    float d3 = dd.w * 0.2f;
    float nh = (float)exp((double)d2) * h;
    float nw = (float)exp((double)d3) * w;
    float ncy = d0 * h + cy;
    float ncx = d1 * w + cx;
    return make_float4(ncy - 0.5f * nh, ncx - 0.5f * nw, ncy + 0.5f * nh, ncx + 0.5f * nw);
}

__device__ __forceinline__ float area_of(const float4 b) {
#pragma clang fp contract(off)
    return (b.z - b.x) * (b.w - b.y);   // same expr/order as reference
}

__device__ __forceinline__ bool iou_gt(const float4 a, const float4 b) {
#pragma clang fp contract(off)
    float areaA = (a.z - a.x) * (a.w - a.y);
    float areaB = (b.z - b.x) * (b.w - b.y);
    float ih = fminf(a.z, b.z) - fmaxf(a.x, b.x);
    ih = fmaxf(ih, 0.0f);
    float iw = fminf(a.w, b.w) - fmaxf(a.y, b.y);
    iw = fmaxf(iw, 0.0f);
    float inter = ih * iw;
    float denom = ((areaA + areaB) - inter) + 1e-9f;
    return (inter / denom) > 0.5f;
}

// same decision with precomputed areas (identical FP expressions/order)
__device__ __forceinline__ bool iou_gt_pre(const float4 a, const float4 b,
                                           float areaA, float areaB) {
#pragma clang fp contract(off)
    float ih = fminf(a.z, b.z) - fmaxf(a.x, b.x);
    ih = fmaxf(ih, 0.0f);
    float iw = fminf(a.w, b.w) - fmaxf(a.y, b.y);
    iw = fmaxf(iw, 0.0f);
    float inter = ih * iw;
    float denom = ((areaA + areaB) - inter) + 1e-9f;
    return (inter / denom) > 0.5f;
}

// reverse-bucket: rb=0 is the HIGHEST score bucket (descending order)
__device__ __forceinline__ int rb_of(u64 key) {
    u32 sb = (u32)(key >> 32);                 // score bits in (0x3F000000, 0x3F800000)
    int rb = 1023 - (int)((sb - 0x3F000000u) >> 13);
    return min(max(rb, 0), 1023);
}

__device__ __forceinline__ u64 lowmask(int n) {
    return (n >= 64) ? ~0ull : ((1ull << n) - 1ull);
}

// descending exclusive scan of histR[1024] -> dstart & cursor
template <int NTHR>
__device__ __forceinline__ void desc_scan(int* histR, int* dstart, int* cursor,
                                          int* wtot, int t) {
    const int PB = NBK / NTHR;
    const int NW = NTHR / 64;
    const int lane = t & 63, w = t >> 6;
    int c[PB], local = 0;
    for (int k = 0; k < PB; ++k) { c[k] = histR[PB * t + k]; local += c[k]; }
    int incl = local;
    for (int d = 1; d < 64; d <<= 1) {
        int v = __shfl_up(incl, d);
        if (lane >= d) incl += v;
    }
    if (lane == 63) wtot[w] = incl;
    __syncthreads();
    int woff = 0;
    for (int i = 0; i < w && i < NW; ++i) woff += wtot[i];
    int run = woff + incl - local;
    for (int k = 0; k < PB; ++k) {
        dstart[PB * t + k] = run;
        cursor[PB * t + k] = run;
        run += c[k];
    }
    __syncthreads();
}

// ---------------- Kernel A: grid-parallel argmax + score bits ----------------
__global__ __launch_bounds__(256) void score_kernel(
    const float* __restrict__ probs,   // (N, L)
    u32* __restrict__ scoreT)          // (L, N) score bits (0 if background)
{
    __shared__ float tile[256 * LL];
    const int a0 = blockIdx.x * 256;
    const int t = threadIdx.x;
    const float4* src = (const float4*)probs + blockIdx.x * 1344;
    float4* dst = (float4*)tile;
    for (int i = t; i < 1344; i += 256) dst[i] = src[i];
    __syncthreads();
    const float* row = tile + t * LL;   // stride 21 (odd): 2-way max, free
    float best = row[0];
    int bi = 0;
    for (int j = 1; j < LL; ++j) {
        float v = row[j];
        if (v > best) { best = v; bi = j; }
    }
    for (int c = 0; c < LL; ++c)
        scoreT[c * NN + a0 + t] = (bi != 0) ? __float_as_uint(row[c]) : 0u;  // coalesced
}

// ---------------- Kernel B: per-class sort + matrix NMS (1024 threads) -------
// Arena: A0=[0,17408) skey/skey3 ; A1=[17408,34816) skey2 (P7 reuse: sup|extq) ;
//        A2=[34816,47104) histR|cursor|dstart ;
//        A3=[47104,63104) cbox(5120)|R(2560)|Tm(5120)|kept(3200) ;
//        A4=[63104,64384) area[320]
#define SMEM_B 64384
#define A1OFF 17408
#define A2OFF 34816
#define A3OFF 47104
#define A4OFF 63104

__global__ __launch_bounds__(1024, 1) void per_class_kernel(
    const u32* __restrict__ scoreT,
    const float* __restrict__ roi,      // (N,4)
    const float* __restrict__ deltas,   // (N, L*4)
    u64* __restrict__ cand_key,         // (L*CAP)
    float4* __restrict__ cand_box,      // (L*CAP)
    u64* __restrict__ fb_key,           // (L)
    float4* __restrict__ fb_box)        // (L)
{
    const int cls = blockIdx.x;
    const int t = threadIdx.x;
    const int lane = t & 63;

    __shared__ char sm[SMEM_B];
    __shared__ int sCnt, sK;
    __shared__ u64 sGmax;
    __shared__ u64 keepm[NCH];
    __shared__ int wtot[16];

    u64* skey  = (u64*)sm;
    u64* skey3 = (u64*)sm;                  // overwrites skey after it's consumed
    u64* skey2 = (u64*)(sm + A1OFF);
    int* histR  = (int*)(sm + A2OFF);
    int* cursor = (int*)(sm + A2OFF + 4096);
    int* dstart = (int*)(sm + A2OFF + 8192);
    float4* cbox = (float4*)(sm + A3OFF);            // [TMAX]
    u64* R  = (u64*)(sm + A3OFF + 5120);             // [NCH*64]
    u64* Tm = (u64*)(sm + A3OFF + 7680);             // [10*64]
    float4* kept = (float4*)(sm + A3OFF + 12800);    // [CAP]
    float* area = (float*)(sm + A4OFF);              // [TMAX]

    if (t == 0) { sCnt = 0; sK = 0; sGmax = 0ull; }
    if (t < CAP) cand_key[cls * CAP + t] = 0ull;
    histR[t] = 0;
    __syncthreads();

    // P1: uint2 load (2 anchors/thread), compact > 0.5, fused hist + block max
    uint2 s2 = ((const uint2*)(scoreT + cls * NN))[t];
    u32 sv[2] = { s2.x, s2.y };
    u64 lq[2];
    int ln = 0;
    u64 lmax = 0ull;
    for (int k = 0; k < 2; ++k) {
        u32 a = 2 * t + k;
        u64 key = ((u64)sv[k] << 32) | (u32)(~a);
        if (key > lmax) lmax = key;
        if (sv[k] > 0x3F000000u) lq[ln++] = key;   // strict score > 0.5
    }
    for (int d = 1; d < 64; d <<= 1) {
        u64 o = shfl_xor_u64(lmax, d);
        if (o > lmax) lmax = o;
    }
    if (lane == 0) atomicMax(&sGmax, lmax);
    int incl = ln;
    for (int d = 1; d < 64; d <<= 1) {
        int v = __shfl_up(incl, d);
        if (lane >= d) incl += v;
    }
    int wsum = __shfl(incl, 63);
    int wbase = 0;
    if (lane == 63) wbase = atomicAdd(&sCnt, wsum);
    wbase = __shfl(wbase, 63);
    int off = wbase + incl - ln;
    for (int j = 0; j < ln; ++j) {
        skey[off + j] = lq[j];
        atomicAdd(&histR[rb_of(lq[j])], 1);
    }
    __syncthreads();
    const int M = sCnt;
    const int TT = min(M, TMAX);

    // per-class fallback: rank-0 box (always kept); max over ALL scores
    if (t == 0) {
        u64 g = sGmax;
        u32 a0 = ~(u32)(g & 0xFFFFFFFFull);
        float4 rb = *(const float4*)(roi + a0 * 4);
        float4 dd = *(const float4*)(deltas + a0 * (LL * 4) + cls * 4);
        fb_box[cls] = decode_box(rb, dd);
        fb_key[cls] = (g & 0xFFFFFFFF00000000ull) | (u32)(~(u32)(cls * NN));
    }

    // P2: scan
    desc_scan<1024>(histR, dstart, cursor, wtot, t);

    // P3: scatter to bucket-grouped order (1 element/thread typical)
    for (int i = t; i < M; i += 1024) {
        u64 k = skey[i];
        int pos = atomicAdd(&cursor[rb_of(k)], 1);
        skey2[pos] = k;
    }
    __syncthreads();   // skey consumed -> region becomes skey3

    // P4: rank-by-count -> sorted skey3 ; fused decode+area for rnk < TT
    for (int p = t; p < M; p += 1024) {
        u64 k = skey2[p];
        int rb = rb_of(k);
        int s = dstart[rb], e = s + histR[rb];
        int rnk = s;
        for (int q = s; q < e; ++q) rnk += (skey2[q] > k) ? 1 : 0;  // independent reads
        skey3[rnk] = k;
        if (rnk < TT) {
            u32 a = ~(u32)(k & 0xFFFFFFFFull);
            float4 rbx = *(const float4*)(roi + a * 4);
            float4 dd = *(const float4*)(deltas + a * (LL * 4) + cls * 4);
            float4 bx = decode_box(rbx, dd);
            cbox[rnk] = bx;
            area[rnk] = area_of(bx);
        }
    }
    __syncthreads();   // skey2 dead

    const int NCHe = (TT + 63) / 64;
    const int NJ = NCHe * (NCHe + 1) / 2;            // jobs (cj,ci) ci<=cj

    // P5: pair-bit matrix with precomputed areas (<=1 task/thread at 1024)
    for (int task = t; task < NJ * 64; task += 1024) {
        const int jobid = task >> 6, j = task & 63;
        int cj = 0, acc = 0;
        while (acc + cj + 1 <= jobid) { acc += cj + 1; ++cj; }
        const int ci = jobid - acc;
        const int gj = cj * 64 + j;
        const int nbj = min(64, TT - cj * 64);
        if (ci == cj) {
            u64 row = 0ull;
            if (j < nbj) {
                float4 bj = cbox[gj];
                float aj = area[gj];
                for (int r2 = j + 1; r2 < nbj; ++r2)
                    if (iou_gt_pre(bj, cbox[cj * 64 + r2], aj, area[cj * 64 + r2]))
                        row |= (1ull << r2);
            }
            R[cj * 64 + j] = row;
        } else {
            u64 wd = 0ull;
            if (j < nbj) {
                float4 bj = cbox[gj];
                float aj = area[gj];
                const float4* cb = cbox + ci * 64;   // broadcast reads
                const float* ca = area + ci * 64;
                for (int i = 0; i < 64; ++i)
                    if (iou_gt_pre(cb[i], bj, ca[i], aj)) wd |= (1ull << i);
            }
            Tm[(cj * (cj - 1) / 2 + ci) * 64 + j] = wd;
        }
    }
    __syncthreads();

    // P6: wave0 barrier-free resolve with sparse skip (overlaps rare)
    if (t < 64) {
        int K = 0;
        for (int cj = 0; cj < NCHe; ++cj) {
            if (K >= CAP) break;
            const int nb = min(64, TT - cj * 64);
            u64 row = R[cj * 64 + t];
            bool ext = (t >= nb);
            for (int ci = 0; ci < cj; ++ci)
                if (Tm[(cj * (cj - 1) / 2 + ci) * 64 + t] & keepm[ci]) ext = true;
            u64 rem = __ballot(ext);
            const u64 nz = __ballot(row != 0ull) & ~rem;
            u64 m = nz;
            while (m) {
                int i = __ffsll(m) - 1;
                u64 ri = shfl_u64(row, i);
                rem |= ri;
                u64 gt = (i == 63) ? 0ull : ~lowmask(i + 1);
                m = nz & ~rem & gt;
            }
            u64 keep = ~rem & lowmask(nb);
            if (t == 0) keepm[cj] = keep;
            if (t < nb && ((keep >> t) & 1ull)) {
                int krank = K + __popcll(keep & lowmask(t));
                if (krank < CAP) {
                    kept[krank] = cbox[cj * 64 + t];
                    int slot = cls * CAP + krank;
                    // ~slot low bits: slot order isomorphic to flat-index order ->
                    // reproduces lax.top_k stable tie-break
                    cand_key[slot] = (skey3[cj * 64 + t] & 0xFFFFFFFF00000000ull) |
                                     (u32)(~(u32)slot);
                    cand_box[slot] = cbox[cj * 64 + t];
                }
            }
            K += __popcll(keep);
        }
        if (t == 0) sK = K;
    }
    __syncthreads();

    // P7: rare exact continuation past TMAX (16 groups of 64; scratch in dead skey2)
    int K = sK;
    if (K < CAP && M > TT) {
        u64* sup = (u64*)(sm + A1OFF);                       // [16][64] = 8 KB
        unsigned char* extq = (unsigned char*)(sm + A1OFF + 8192);  // [16][64]
        const int g = t >> 6, r = t & 63;
        for (int base = TT; base < M; base += 64) {
            K = sK;
            if (K >= CAP) break;
            const int nb = min(64, M - base);
            if (t < nb) {
                u32 a = ~(u32)(skey3[base + t] & 0xFFFFFFFFull);
                float4 rbx = *(const float4*)(roi + a * 4);
                float4 dd = *(const float4*)(deltas + a * (LL * 4) + cls * 4);
                cbox[t] = decode_box(rbx, dd);
            }
            __syncthreads();
            u64 bits = 0ull;
            if (r < nb) {
                float4 br = cbox[r];
                int lo = max(r + 1, g * 4), hi = min(nb, (g + 1) * 4);
                for (int r2 = lo; r2 < hi; ++r2)
                    if (iou_gt(br, cbox[r2])) bits |= (1ull << r2);
            }
            sup[g * 64 + r] = bits;
            bool f = false;
            if (r < nb) {
                float4 bm = cbox[r];
                int per = (K + 15) >> 4;
                int e0 = g * per, e1 = min(K, e0 + per);
                for (int e = e0; e < e1; ++e)
                    if (iou_gt(kept[e], bm)) { f = true; break; }
            }
            extq[g * 64 + r] = f ? 1 : 0;
            __syncthreads();
            if (t < 64) {
                u64 row = 0ull;
                int extv = 0;
                for (int j = 0; j < 16; ++j) { row |= sup[j * 64 + t]; extv |= extq[j * 64 + t]; }
                bool ext = (t < nb) ? (extv != 0) : true;
                u64 rem = __ballot(ext);
                const u64 nz = __ballot(row != 0ull) & ~rem;
                u64 m = nz;
                while (m) {
                    int i = __ffsll(m) - 1;
                    u64 ri = shfl_u64(row, i);
                    rem |= ri;
                    u64 gt = (i == 63) ? 0ull : ~lowmask(i + 1);
                    m = nz & ~rem & gt;
                }
                u64 keep = ~rem & lowmask(nb);
                if (t < nb && ((keep >> t) & 1ull)) {
                    int krank = K + __popcll(keep & lowmask(t));
                    if (krank < CAP) {
                        kept[krank] = cbox[t];
                        int slot = cls * CAP + krank;
                        cand_key[slot] = (skey3[base + t] & 0xFFFFFFFF00000000ull) |
                                         (u32)(~(u32)slot);
                        cand_box[slot] = cbox[t];
                    }
                }
                if (t == 0) sK = K + __popcll(keep);
            }
            __syncthreads();
        }
    }
}

// ---------------- Kernel C: global top-200, chain-free (512 threads) ---------
__global__ __launch_bounds__(512) void topk_kernel(
    const u64* __restrict__ cand_key,
    const float4* __restrict__ cand_box,
    const u64* __restrict__ fb_key,
    const float4* __restrict__ fb_box,
    float* __restrict__ out)   // [800 boxes][200 labels][200 scores]
{
    const int t = threadIdx.x;
    __shared__ u64 keys[TOT];
    __shared__ int histR[NBK], cursor[NBK], dstart[NBK];
    __shared__ u64 arr[ARRCAP];
    __shared__ u64 outk[CAP];
    __shared__ int wtot[8];
    __shared__ int sRbstar;

    for (int i = t; i < NBK; i += 512) histR[i] = 0;
    if (t < CAP) outk[t] = 0ull;
    if (t == 0) sRbstar = NBK - 1;
    __syncthreads();

    // load 4200 keys as ulong2 (independent, pipelined) + histogram
    const ulong2* ck2 = (const ulong2*)cand_key;
    for (int i = t; i < TOT / 2; i += 512) {
        ulong2 k2 = ck2[i];
        keys[2 * i]     = k2.x;
        keys[2 * i + 1] = k2.y;
        if (k2.x != 0ull) atomicAdd(&histR[rb_of(k2.x)], 1);
        if (k2.y != 0ull) atomicAdd(&histR[rb_of(k2.y)], 1);
    }
    __syncthreads();
    desc_scan<512>(histR, dstart, cursor, wtot, t);
    // unique crossing bucket: dstart < CAP <= dstart+len (single writer, no storm)
    for (int k = 0; k < 2; ++k) {
        int rb = 2 * t + k;
        if (dstart[rb] < CAP && dstart[rb] + histR[rb] >= CAP) sRbstar = rb;
    }
    __syncthreads();
    const int rbstar = sRbstar;

    // scatter candidates in buckets <= rbstar (bucket-grouped, order-agnostic)
    for (int i = t; i < TOT; i += 512) {
        u64 k = keys[i];
        if (k != 0ull) {
            int rb = rb_of(k);
            if (rb <= rbstar) {
                int pos = atomicAdd(&cursor[rb], 1);
                if (pos < ARRCAP) arr[pos] = k;
            }
        }
    }
    __syncthreads();

    // rank-by-count within buckets: exact global rank, direct scatter to outk
    const int E = min(dstart[rbstar] + histR[rbstar], ARRCAP);
    for (int p = t; p < E; p += 512) {
        u64 k = arr[p];
        int rb = rb_of(k);
        int s = dstart[rb], e = min(s + histR[rb], ARRCAP);
        int rnk = s;
        for (int q = s; q < e; ++q) rnk += (arr[q] > k) ? 1 : 0;  // independent reads
        if (rnk < CAP) outk[rnk] = k;
    }
    __syncthreads();

    for (int o = t; o < CAP; o += 512) {
        u64 key = outk[o];
        float4 b = make_float4(0.0f, 0.0f, 0.0f, 0.0f);
        float lab = 0.0f, sc = 0.0f;
        if (key != 0ull) {   // all candidates have score > 0.5 -> valid
            u32 slot = ~(u32)(key & 0xFFFFFFFFull);
            sc = __uint_as_float((u32)(key >> 32));
            lab = (float)(slot / CAP);
            b = clip01(cand_box[slot]);
        }
        out[o * 4 + 0] = b.x;
        out[o * 4 + 1] = b.y;
        out[o * 4 + 2] = b.z;
        out[o * 4 + 3] = b.w;
        out[4 * CAP + o] = lab;
        out[5 * CAP + o] = sc;
    }
    __syncthreads();

    // fallback: no candidate anywhere -> global best kept box at slot 0
    if (t == 0 && outk[0] == 0ull) {
        u64 best = 0ull;
        int bc = 0;
        for (int c = 0; c < LL; ++c) {
            u64 k = fb_key[c];
            if (k > best) { best = k; bc = c; }
        }
        float bs = __uint_as_float((u32)(best >> 32));
        if (bs >= 0.001f) {
            float4 bb = clip01(fb_box[bc]);
            out[0] = bb.x; out[1] = bb.y; out[2] = bb.z; out[3] = bb.w;
            out[4 * CAP] = (float)bc;
            out[5 * CAP] = bs;
        }
    }
}

extern "C" void kernel_launch(void* const* d_in, const int* in_sizes, int n_in,
                              void* d_out, int out_size, void* d_ws, size_t ws_size,
                              hipStream_t stream) {
    const float* roi    = (const float*)d_in[0];   // (1,2048,4)
    const float* deltas = (const float*)d_in[1];   // (1,2048,84)
    const float* probs  = (const float*)d_in[2];   // (1,2048,21)
    float* out = (float*)d_out;

    char* ws = (char*)d_ws;
    u32*    scoreT   = (u32*)ws;                   // 21*2048*4 = 172032
    u64*    cand_key = (u64*)(ws + 172032);        // 4200*8   = 33600 -> 205632
    float4* cand_box = (float4*)(ws + 205632);     // 4200*16  = 67200 -> 272832
    u64*    fb_key   = (u64*)(ws + 272832);        // 168 -> 273000
    float4* fb_box   = (float4*)(ws + 273008);     // 336 -> 273344

    score_kernel<<<NN / 256, 256, 0, stream>>>(probs, scoreT);
    per_class_kernel<<<LL, 1024, 0, stream>>>(scoreT, roi, deltas,
                                              cand_key, cand_box, fb_key, fb_box);
    topk_kernel<<<1, 512, 0, stream>>>(cand_key, cand_box, fb_key, fb_box, out);
}